// Round 12
// baseline (6519.874 us; speedup 1.0000x reference)
//
#include <hip/hip_runtime.h>

// B=256, T=512, I=128, H=256, 4H=1024
// PER-STEP KERNEL GRAPH: 512 encoder + 512 decoder kernels, one per time-step.
// Kernel boundary = device-wide release/acquire (hardware-provided; proven in-session
// by pack_kernel -> lstm_main plain-store/plain-load visibility across all XCDs).
// => zero custom sync, all plain cached memory ops, replay-safe by construction.
// Each step kernel: 256 blocks x 64 threads (1 wave/CU). Block (rt, cg) computes the
// gate tile [16 rows x 64 gate-cols] (K=384) with weights read as B-fragments straight
// from L2-hot packed buffers; h exchanged via a fragment-layout bf16 buffer (coalesced
// 16 B/lane loads); c in a global fp32 buffer. Decoder computes pred redundantly
// per block (rows-local) so pred->gates stays inside one kernel.

typedef __bf16 bf16;
typedef bf16 bf16x8 __attribute__((ext_vector_type(8)));
typedef float f32x4 __attribute__((ext_vector_type(4)));
typedef unsigned u32;

#define MFMA16(a, b, c) __builtin_amdgcn_mfma_f32_16x16x32_bf16((a), (b), (c), 0, 0, 0)

__device__ __forceinline__ float sigm(float x) { return 1.0f / (1.0f + __expf(-x)); }
__device__ __forceinline__ float tanhfast(float x) { return 1.0f - 2.0f / (__expf(2.0f * x) + 1.0f); }

// ---------------- weight packing (fragment layout, unchanged from r4) ----------------
__global__ void pack_kernel(const float* __restrict__ eWih, const float* __restrict__ eWhh,
                            const float* __restrict__ dWih, const float* __restrict__ dWhh,
                            const float* __restrict__ linW,
                            bf16* __restrict__ encB, bf16* __restrict__ decB, bf16* __restrict__ linB) {
    int idx = blockIdx.x * 256 + threadIdx.x;  // 0 .. 819199
    if (idx < 786432) {
        int which = idx / 393216;          // 0 = enc, 1 = dec
        int id = idx % 393216;
        int cg = id / 24576;
        int rem = id % 24576;
        int ks = rem / 2048;
        int n = (rem / 512) & 3;
        int lane = (rem >> 3) & 63;
        int e = rem & 7;
        int k = ks * 32 + (lane >> 4) * 8 + e;
        int col = n * 256 + cg * 16 + (lane & 15);
        const float* Wih = which ? dWih : eWih;
        const float* Whh = which ? dWhh : eWhh;
        float v = (k < 128) ? Wih[col * 128 + k] : Whh[col * 256 + (k - 128)];
        (which ? decB : encB)[id] = (bf16)v;
    } else if (idx < 819200) {
        int i3 = idx - 786432;             // 0 .. 32767
        int ks = i3 >> 12;
        int n = (i3 >> 9) & 7;
        int lane = (i3 >> 3) & 63;
        int e = i3 & 7;
        int k = ks * 32 + (lane >> 4) * 8 + e;
        int col = n * 16 + (lane & 15);
        linB[i3] = (bf16)linW[col * 256 + k];
    }
}

// zero h frag buffers (both phases) + c buffer — every launch (replay safety)
__global__ void zero_kernel(u32* __restrict__ p) {
    int i = blockIdx.x * 256 + threadIdx.x;
    if (i < 131072) p[i] = 0u;   // 65536 words h (2 x 65536 bf16) + 65536 words c (fp32)
}

// h fragment layout (per phase, 65536 bf16):
//   element ((rt*8 + ks)*64 + lane)*8 + e  ==  h[rt*16 + (lane&15)][ks*32 + (lane>>4)*8 + e]

// ---------------- encoder step ----------------
__global__ __launch_bounds__(64, 1)
void enc_step(const float* __restrict__ x,
              const float* __restrict__ bih, const float* __restrict__ bhh,
              const bf16* __restrict__ W,
              const bf16* __restrict__ hr, bf16* __restrict__ hw,
              float* __restrict__ cbuf, int t) {
    const int bid = blockIdx.x;
    const int rt = bid >> 4, cg = bid & 15;
    const int lane = threadIdx.x;
    const int l15 = lane & 15, l4 = lane >> 4;
    const int ucol = cg * 16 + l15;          // this lane's hidden unit (epilogue)
    const int prow = rt * 16 + l4 * 4;       // epilogue row base

    const bf16* Wb = W + cg * 24576;

    // h A-fragments (coalesced 16 B/lane)
    bf16x8 ha[8];
    #pragma unroll
    for (int ks = 0; ks < 8; ks++)
        ha[ks] = *(const bf16x8*)&hr[((rt * 8 + ks) * 64 + lane) * 8];

    f32x4 acc[4];
    #pragma unroll
    for (int n = 0; n < 4; n++) acc[n] = (f32x4){0.f, 0.f, 0.f, 0.f};

    // x part (K 0..127)
    const float* xb = x + ((size_t)(rt * 16 + l15) * 512 + t) * 128 + l4 * 8;
    #pragma unroll
    for (int ks = 0; ks < 4; ks++) {
        f32x4 xa = *(const f32x4*)(xb + ks * 32);
        f32x4 xc = *(const f32x4*)(xb + ks * 32 + 4);
        bf16x8 a;
        a[0] = (bf16)xa[0]; a[1] = (bf16)xa[1]; a[2] = (bf16)xa[2]; a[3] = (bf16)xa[3];
        a[4] = (bf16)xc[0]; a[5] = (bf16)xc[1]; a[6] = (bf16)xc[2]; a[7] = (bf16)xc[3];
        #pragma unroll
        for (int n = 0; n < 4; n++) {
            bf16x8 b = *(const bf16x8*)&Wb[((ks * 4 + n) * 64 + lane) * 8];
            acc[n] = MFMA16(a, b, acc[n]);
        }
    }
    // h part (K 128..383)
    #pragma unroll
    for (int ks = 0; ks < 8; ks++) {
        #pragma unroll
        for (int n = 0; n < 4; n++) {
            bf16x8 b = *(const bf16x8*)&Wb[(((ks + 4) * 4 + n) * 64 + lane) * 8];
            acc[n] = MFMA16(ha[ks], b, acc[n]);
        }
    }
    float bias[4];
    #pragma unroll
    for (int g = 0; g < 4; g++) bias[g] = bih[g * 256 + ucol] + bhh[g * 256 + ucol];

    const int ks2 = ucol >> 5, e2 = ucol & 7;
    #pragma unroll
    for (int r = 0; r < 4; r++) {
        float gi = sigm(acc[0][r] + bias[0]);
        float gf = sigm(acc[1][r] + bias[1]);
        float gg = tanhfast(acc[2][r] + bias[2]);
        float go = sigm(acc[3][r] + bias[3]);
        size_t ci = (size_t)(prow + r) * 256 + ucol;
        float cv = gf * cbuf[ci] + gi * gg;
        cbuf[ci] = cv;
        float h = go * tanhfast(cv);
        int lh = (((ucol >> 3) & 3) << 4) | (l4 * 4 + r);
        hw[((rt * 8 + ks2) * 64 + lh) * 8 + e2] = (bf16)h;
    }
}

// ---------------- decoder step (pred then gates; last=k==511 pred-only) ----------------
__global__ __launch_bounds__(64, 1)
void dec_step(const float* __restrict__ bih, const float* __restrict__ bhh,
              const float* __restrict__ lin_b,
              const bf16* __restrict__ W, const bf16* __restrict__ L,
              const bf16* __restrict__ hr, bf16* __restrict__ hw,
              float* __restrict__ cbuf, float* __restrict__ out, int k) {
    __shared__ bf16 pst[16 * 136];   // pred tile [row16][col128], pitch 136

    const int bid = blockIdx.x;
    const int rt = bid >> 4, cg = bid & 15;
    const int lane = threadIdx.x;
    const int l15 = lane & 15, l4 = lane >> 4;
    const int ucol = cg * 16 + l15;
    const int prow = rt * 16 + l4 * 4;

    // h A-fragments (reused for pred and gates h-part)
    bf16x8 ha[8];
    #pragma unroll
    for (int ks = 0; ks < 8; ks++)
        ha[ks] = *(const bf16x8*)&hr[((rt * 8 + ks) * 64 + lane) * 8];

    // pred = sigmoid(h @ lin_W^T + lin_b), [16 rows x 128], redundant per block
    f32x4 pacc[8];
    #pragma unroll
    for (int n = 0; n < 8; n++) pacc[n] = (f32x4){0.f, 0.f, 0.f, 0.f};
    #pragma unroll
    for (int ks = 0; ks < 8; ks++) {
        #pragma unroll
        for (int n = 0; n < 8; n++) {
            bf16x8 b = *(const bf16x8*)&L[((ks * 8 + n) * 64 + lane) * 8];
            pacc[n] = MFMA16(ha[ks], b, pacc[n]);
        }
    }
    float lb[8];
    #pragma unroll
    for (int n = 0; n < 8; n++) lb[n] = lin_b[n * 16 + l15];

    const int t_out = 511 - k;
    const int ncg = cg >> 1, hsel = cg & 1;   // this block's out col slice
    #pragma unroll
    for (int n = 0; n < 8; n++) {
        #pragma unroll
        for (int r = 0; r < 4; r++) {
            float p = sigm(pacc[n][r] + lb[n]);
            pst[(l4 * 4 + r) * 136 + n * 16 + l15] = (bf16)p;
            if (n == ncg && (l15 >> 3) == hsel)
                out[((size_t)(prow + r) * 512 + t_out) * 128 + n * 16 + l15] = p;
        }
    }
    if (k == 511) return;   // last step: prediction only

    // same-wave LDS RAW: wait writes, fence scheduler (guide rule #18)
    asm volatile("s_waitcnt lgkmcnt(0)" ::: "memory");
    __builtin_amdgcn_sched_barrier(0);

    // gates = [pred | h] @ Wdec^T
    const bf16* Wb = W + cg * 24576;
    f32x4 acc[4];
    #pragma unroll
    for (int n = 0; n < 4; n++) acc[n] = (f32x4){0.f, 0.f, 0.f, 0.f};
    #pragma unroll
    for (int ks = 0; ks < 8; ks++) {
        #pragma unroll
        for (int n = 0; n < 4; n++) {
            bf16x8 b = *(const bf16x8*)&Wb[(((ks + 4) * 4 + n) * 64 + lane) * 8];
            acc[n] = MFMA16(ha[ks], b, acc[n]);
        }
    }
    const bf16* pr = pst + l15 * 136 + l4 * 8;
    #pragma unroll
    for (int ks = 0; ks < 4; ks++) {
        bf16x8 a = *(const bf16x8*)(pr + ks * 32);
        #pragma unroll
        for (int n = 0; n < 4; n++) {
            bf16x8 b = *(const bf16x8*)&Wb[((ks * 4 + n) * 64 + lane) * 8];
            acc[n] = MFMA16(a, b, acc[n]);
        }
    }
    float bias[4];
    #pragma unroll
    for (int g = 0; g < 4; g++) bias[g] = bih[g * 256 + ucol] + bhh[g * 256 + ucol];

    const int ks2 = ucol >> 5, e2 = ucol & 7;
    #pragma unroll
    for (int r = 0; r < 4; r++) {
        float gi = sigm(acc[0][r] + bias[0]);
        float gf = sigm(acc[1][r] + bias[1]);
        float gg = tanhfast(acc[2][r] + bias[2]);
        float go = sigm(acc[3][r] + bias[3]);
        size_t ci = (size_t)(prow + r) * 256 + ucol;
        float cv = gf * cbuf[ci] + gi * gg;
        cbuf[ci] = cv;
        float h = go * tanhfast(cv);
        int lh = (((ucol >> 3) & 3) << 4) | (l4 * 4 + r);
        hw[((rt * 8 + ks2) * 64 + lh) * 8 + e2] = (bf16)h;
    }
}

extern "C" void kernel_launch(void* const* d_in, const int* in_sizes, int n_in,
                              void* d_out, int out_size, void* d_ws, size_t ws_size,
                              hipStream_t stream) {
    const float* x    = (const float*)d_in[0];
    const float* eWih = (const float*)d_in[1];
    const float* eWhh = (const float*)d_in[2];
    const float* ebih = (const float*)d_in[3];
    const float* ebhh = (const float*)d_in[4];
    const float* dWih = (const float*)d_in[5];
    const float* dWhh = (const float*)d_in[6];
    const float* dbih = (const float*)d_in[7];
    const float* dbhh = (const float*)d_in[8];
    const float* linW = (const float*)d_in[9];
    const float* linb = (const float*)d_in[10];
    float* out = (float*)d_out;

    // workspace layout (~2.2 MB)
    bf16* encB = (bf16*)d_ws;             // 393216 bf16
    bf16* decB = encB + 393216;           // 393216 bf16
    bf16* linB = decB + 393216;           // 32768 bf16
    bf16* hbuf = linB + 32768;            // 2 phases x 65536 bf16 (fragment layout)
    float* cbuf = (float*)(hbuf + 131072);// 256 x 256 fp32

    hipLaunchKernelGGL(pack_kernel, dim3(3200), dim3(256), 0, stream,
                       eWih, eWhh, dWih, dWhh, linW, encB, decB, linB);
    hipLaunchKernelGGL(zero_kernel, dim3(512), dim3(256), 0, stream, (u32*)hbuf);

    for (int t = 0; t < 512; t++) {
        hipLaunchKernelGGL(enc_step, dim3(256), dim3(64), 0, stream,
                           x, ebih, ebhh, encB,
                           hbuf + (t & 1) * 65536, hbuf + ((t + 1) & 1) * 65536,
                           cbuf, t);
    }
    for (int k = 0; k < 512; k++) {
        hipLaunchKernelGGL(dec_step, dim3(256), dim3(64), 0, stream,
                           dbih, dbhh, linb, decB, linB,
                           hbuf + (k & 1) * 65536, hbuf + ((k + 1) & 1) * 65536,
                           cbuf, out, k);
    }
}

// Round 13
// 4833.974 us; speedup vs baseline: 1.3488x; 1.3488x over previous
//
#include <hip/hip_runtime.h>

// B=256, T=512, I=128, H=256, 4H=1024
// 64 blocks = 4 row-groups x 16 col-groups. EXACT r4 protocol (best measured: 4865us)
// with ONE change: the flag poll is a 4-deep pipelined poll (4 outstanding flag loads,
// s_waitcnt vmcnt(3) waits the oldest — in-order completion, m135), cutting detect
// granularity from ~1 fabric RT to ~RT/4 with zero added traffic. Stray in-flight
// flag loads at detect are never drained; their registers are kept alive via a "+v"
// liveness fence at the next iteration's vmcnt(0). x-prefetch is 8 counted asm loads
// issued before the flag quad so the in-order vmcnt rule stays exact.

typedef __bf16 bf16;
typedef bf16 bf16x8 __attribute__((ext_vector_type(8)));
typedef float f32x4 __attribute__((ext_vector_type(4)));
typedef unsigned u32;
typedef u32 u32x4 __attribute__((ext_vector_type(4)));

#define MFMA16(a, b, c) __builtin_amdgcn_mfma_f32_16x16x32_bf16((a), (b), (c), 0, 0, 0)
#define AT_STORE_DEV(p, v) __hip_atomic_store((p), (v), __ATOMIC_RELAXED, __HIP_MEMORY_SCOPE_AGENT)

__device__ __forceinline__ float sigm(float x) { return 1.0f / (1.0f + __expf(-x)); }
__device__ __forceinline__ float tanhfast(float x) { return 1.0f - 2.0f / (__expf(2.0f * x) + 1.0f); }

// device-coherent ops (L1+L2 bypass) — r4-proven paths
__device__ __forceinline__ u32x4 load_hx4(const u32* p) {
    u32x4 v;
    asm volatile("global_load_dwordx4 %0, %1, off sc0 sc1" : "=v"(v) : "v"(p));
    return v;
}
__device__ __forceinline__ void store_h(u32* p, u32 v) {
    asm volatile("global_store_dword %0, %1, off sc0 sc1" :: "v"(p), "v"(v) : "memory");
}
// plain cached x-load as asm (counted; keeps compiler's vmcnt model out of the loop)
__device__ __forceinline__ f32x4 load_x4a(const float* p) {
    f32x4 v;
    asm volatile("global_load_dwordx4 %0, %1, off" : "=v"(v) : "v"(p));
    return v;
}
#define DRAIN0() do { asm volatile("s_waitcnt vmcnt(0)" ::: "memory"); \
                      __builtin_amdgcn_sched_barrier(0); } while (0)
#define WAIT3()  do { asm volatile("s_waitcnt vmcnt(3)" ::: "memory"); \
                      __builtin_amdgcn_sched_barrier(0); } while (0)
#define ISSUE_F(reg) asm volatile("global_load_dword %0, %1, off sc0 sc1" \
                                  : "=v"(reg) : "v"(pollp))
// 4-deep pipelined poll: break leaves <=3 strays in flight (handled by liveness fence)
#define PIPE_POLL(target)                                                         \
    {                                                                             \
        ISSUE_F(f0); ISSUE_F(f1); ISSUE_F(f2); ISSUE_F(f3);                       \
        int sp = 0;                                                               \
        for (;;) {                                                                \
            WAIT3(); if (__all((int)(f0 >= (u32)(target)))) break; ISSUE_F(f0);   \
            WAIT3(); if (__all((int)(f1 >= (u32)(target)))) break; ISSUE_F(f1);   \
            WAIT3(); if (__all((int)(f2 >= (u32)(target)))) break; ISSUE_F(f2);   \
            WAIT3(); if (__all((int)(f3 >= (u32)(target)))) break; ISSUE_F(f3);   \
            if (++sp > 40000) break;  /* fail-fast: wrong answer, never a hang */  \
        }                                                                         \
        __builtin_amdgcn_sched_barrier(0);                                        \
    }
#define F_LIVENESS() asm volatile("" : "+v"(f0), "+v"(f1), "+v"(f2), "+v"(f3))

// ---------------- weight packing (fragment layout, unchanged) ----------------
__global__ void pack_kernel(const float* __restrict__ eWih, const float* __restrict__ eWhh,
                            const float* __restrict__ dWih, const float* __restrict__ dWhh,
                            const float* __restrict__ linW,
                            bf16* __restrict__ encB, bf16* __restrict__ decB, bf16* __restrict__ linB) {
    int idx = blockIdx.x * 256 + threadIdx.x;  // 0 .. 819199
    if (idx < 786432) {
        int which = idx / 393216;          // 0 = enc, 1 = dec
        int id = idx % 393216;
        int cg = id / 24576;
        int rem = id % 24576;
        int ks = rem / 2048;
        int n = (rem / 512) & 3;
        int lane = (rem >> 3) & 63;
        int e = rem & 7;
        int k = ks * 32 + (lane >> 4) * 8 + e;
        int col = n * 256 + cg * 16 + (lane & 15);
        const float* Wih = which ? dWih : eWih;
        const float* Whh = which ? dWhh : eWhh;
        float v = (k < 128) ? Wih[col * 128 + k] : Whh[col * 256 + (k - 128)];
        (which ? decB : encB)[id] = (bf16)v;
    } else if (idx < 819200) {
        int i3 = idx - 786432;             // 0 .. 32767
        int ks = i3 >> 12;
        int n = (i3 >> 9) & 7;
        int lane = (i3 >> 3) & 63;
        int e = i3 & 7;
        int k = ks * 32 + (lane >> 4) * 8 + e;
        int col = n * 16 + (lane & 15);
        linB[i3] = (bf16)linW[col * 256 + k];
    }
}

__global__ void zero_kernel(unsigned* __restrict__ p) {
    int i = blockIdx.x * 256 + threadIdx.x;
    // h ping-pong (65536 words) + flags (256 words)
    if (i < 65792) AT_STORE_DEV(&p[i], 0u);
}

// ---------------- main persistent kernel ----------------
__global__ __launch_bounds__(256, 1)
void lstm_main(const float* __restrict__ x,
               const float* __restrict__ eb_ih, const float* __restrict__ eb_hh,
               const float* __restrict__ db_ih, const float* __restrict__ db_hh,
               const float* __restrict__ lin_b,
               const bf16* __restrict__ encB, const bf16* __restrict__ decB,
               const bf16* __restrict__ linB,
               u32* __restrict__ hbuf32, u32* __restrict__ flags,
               float* __restrict__ out) {
    __shared__ bf16 Bg[24576];         // 48 KB gate-weight fragments (this cg)
    __shared__ bf16 Lw[32768];         // 64 KB lin_W fragments (decoder)
    __shared__ bf16 Pst[4 * 16 * 136]; // 17 KB pred staging, per-wave, pitch 136

    const int bid = blockIdx.x;
    const int rg = bid >> 4;           // row-group 0..3  (64 batch rows)
    const int cg = bid & 15;           // col-group 0..15 (16 hidden units)
    const int tid = threadIdx.x;
    const int w = tid >> 6;
    const int lane = tid & 63;
    const int l15 = lane & 15, l4 = lane >> 4;
    const int rbase = rg * 64 + w * 16;       // wave's 16 batch rows
    const int ucol = cg * 16 + l15;           // this lane's hidden unit
    const int arow = rbase + l15;             // A-fragment row this lane loads
    const int k0 = l4 * 8;                    // A-fragment k sub-offset
    const int prow = rbase + l4 * 4;          // epilogue row base

    // h fragment layout: hbuf[phase][rt=16][ks=8][256 words]  (r4-proven)
    const int rt = rg * 4 + w;                // this wave's row tile
    const int htile_w = (cg >> 1) * 256;      // writer's ks-tile
    const int hgrp = ((cg & 1) * 2 + (l15 >> 3)) * 16;
    const int widx = (l15 & 7) >> 1;

    // load encoder gate weights into LDS
    {
        const f32x4* src = (const f32x4*)(encB + cg * 24576);
        f32x4* dst = (f32x4*)Bg;
        #pragma unroll
        for (int i = 0; i < 12; i++) dst[tid + 256 * i] = src[tid + 256 * i];
    }
    float bias_g[4];
    #pragma unroll
    for (int g = 0; g < 4; g++) bias_g[g] = eb_ih[g * 256 + ucol] + eb_hh[g * 256 + ucol];
    __syncthreads();

    u32* myflag = flags + rg * 64 + cg;          // 256 B per rg (r4 layout)
    const u32* pollp = flags + rg * 64 + l15;    // 16-lane wide poll
    u32 stepno = 0;
    float c[4] = {0.f, 0.f, 0.f, 0.f};
    u32 f0 = 0, f1 = 0, f2 = 0, f3 = 0;          // pipelined poll registers

    const float* xrow = x + (size_t)arow * 512 * 128 + k0;  // x[arow][t][k0+..]

    // preload x fragments for t=0 (plain; nothing else outstanding yet)
    f32x4 xr[8];
    #pragma unroll
    for (int i = 0; i < 4; i++) {
        xr[2 * i]     = *(const f32x4*)(xrow + i * 32);
        xr[2 * i + 1] = *(const f32x4*)(xrow + i * 32 + 4);
    }

    // =================== encoder: 512 steps ===================
    for (int t = 0; t < 512; t++) {
        const u32* hr32 = hbuf32 + (t & 1) * 32768;
        u32* hw32 = hbuf32 + ((t + 1) & 1) * 32768;

        // issue 8 coalesced h-tile loads
        u32x4 hv[8];
        const u32* hb = hr32 + rt * 2048 + lane * 4;
        #pragma unroll
        for (int ks = 0; ks < 8; ks++) hv[ks] = load_hx4(hb + ks * 256);

        f32x4 acc[4];
        #pragma unroll
        for (int n = 0; n < 4; n++) acc[n] = (f32x4){0.f, 0.f, 0.f, 0.f};

        // x part (K 0..127) from prefetched regs — overlaps h-load flight
        #pragma unroll
        for (int ks = 0; ks < 4; ks++) {
            f32x4 xa = xr[2 * ks], xb = xr[2 * ks + 1];
            bf16x8 a;
            a[0] = (bf16)xa[0]; a[1] = (bf16)xa[1]; a[2] = (bf16)xa[2]; a[3] = (bf16)xa[3];
            a[4] = (bf16)xb[0]; a[5] = (bf16)xb[1]; a[6] = (bf16)xb[2]; a[7] = (bf16)xb[3];
            #pragma unroll
            for (int n = 0; n < 4; n++) {
                bf16x8 b = *(const bf16x8*)&Bg[((ks * 4 + n) * 64 + lane) * 8];
                acc[n] = MFMA16(a, b, acc[n]);
            }
        }
        DRAIN0();          // h resident; all strays (flag/x) complete
        F_LIVENESS();      // poll regs reusable only from here

        // h part (K 128..383)
        #pragma unroll
        for (int ks = 0; ks < 8; ks++) {
            bf16x8 a = __builtin_bit_cast(bf16x8, hv[ks]);
            #pragma unroll
            for (int n = 0; n < 4; n++) {
                bf16x8 b = *(const bf16x8*)&Bg[(((ks + 4) * 4 + n) * 64 + lane) * 8];
                acc[n] = MFMA16(a, b, acc[n]);
            }
        }
        // epilogue: packed fragment-layout h stores
        #pragma unroll
        for (int r = 0; r < 4; r++) {
            float gi = sigm(acc[0][r] + bias_g[0]);
            float gf = sigm(acc[1][r] + bias_g[1]);
            float gg = tanhfast(acc[2][r] + bias_g[2]);
            float go = sigm(acc[3][r] + bias_g[3]);
            c[r] = gf * c[r] + gi * gg;
            float h = go * tanhfast(c[r]);
            unsigned hvv = (unsigned)__builtin_bit_cast(unsigned short, (bf16)h);
            unsigned hp = __shfl_xor(hvv, 1);
            if (!(lane & 1))
                store_h(&hw32[rt * 2048 + htile_w + (hgrp + l4 * 4 + r) * 4 + widx],
                        hvv | (hp << 16));
        }
        // barrier: syncthreads (drains stores) -> flag -> x prefetch -> pipelined poll
        stepno++;
        __syncthreads();
        if (tid == 0) store_h(myflag, stepno);
        {
            int tn = t < 511 ? t + 1 : 511;
            const float* xb2 = xrow + (size_t)tn * 128;
            #pragma unroll
            for (int i = 0; i < 4; i++) {
                xr[2 * i]     = load_x4a(xb2 + i * 32);
                xr[2 * i + 1] = load_x4a(xb2 + i * 32 + 4);
            }
        }
        PIPE_POLL(stepno);
    }
    DRAIN0();   // drain final strays before phase switch
    F_LIVENESS();

    // =================== switch to decoder weights ===================
    __syncthreads();
    {
        const f32x4* src = (const f32x4*)(decB + cg * 24576);
        f32x4* dst = (f32x4*)Bg;
        #pragma unroll
        for (int i = 0; i < 12; i++) dst[tid + 256 * i] = src[tid + 256 * i];
        const f32x4* s2 = (const f32x4*)linB;
        f32x4* d2 = (f32x4*)Lw;
        #pragma unroll
        for (int i = 0; i < 16; i++) d2[tid + 256 * i] = s2[tid + 256 * i];
    }
    float bias_d[4];
    #pragma unroll
    for (int g = 0; g < 4; g++) bias_d[g] = db_ih[g * 256 + ucol] + db_hh[g * 256 + ucol];
    float lbias[8];
    #pragma unroll
    for (int n = 0; n < 8; n++) lbias[n] = lin_b[n * 16 + l15];
    __syncthreads();

    const int ncg = cg >> 1;   // out columns this block writes: n == ncg, half == (cg&1)
    const int hsel = cg & 1;

    // =================== decoder: pred(k) then gates(k) ===================
    for (int k = 0; k < 512; k++) {
        const u32* hr32 = hbuf32 + (k & 1) * 32768;

        u32x4 hv[8];
        const u32* hb = hr32 + rt * 2048 + lane * 4;
        #pragma unroll
        for (int ks = 0; ks < 8; ks++) hv[ks] = load_hx4(hb + ks * 256);
        DRAIN0();
        F_LIVENESS();
        bf16x8 ha[8];
        #pragma unroll
        for (int ks = 0; ks < 8; ks++) ha[ks] = __builtin_bit_cast(bf16x8, hv[ks]);

        // pred = sigmoid(h @ lin_W^T + lin_b)  [64 x 128], redundant per block
        f32x4 pacc[8];
        #pragma unroll
        for (int n = 0; n < 8; n++) pacc[n] = (f32x4){0.f, 0.f, 0.f, 0.f};
        #pragma unroll
        for (int ks = 0; ks < 8; ks++) {
            #pragma unroll
            for (int n = 0; n < 8; n++) {
                bf16x8 b = *(const bf16x8*)&Lw[((ks * 8 + n) * 64 + lane) * 8];
                pacc[n] = MFMA16(ha[ks], b, pacc[n]);
            }
        }
        const int t_out = 511 - k;
        float* obase = out + (size_t)prow * 512 * 128 + (size_t)t_out * 128;
        bf16* pst_w = Pst + w * 2176;
        #pragma unroll
        for (int n = 0; n < 8; n++) {
            #pragma unroll
            for (int r = 0; r < 4; r++) {
                float p = sigm(pacc[n][r] + lbias[n]);
                pst_w[(l4 * 4 + r) * 136 + n * 16 + l15] = (bf16)p;
                if (n == ncg && (l15 >> 3) == hsel)
                    obase[(size_t)r * 512 * 128 + n * 16 + l15] = p;
            }
        }
        if (k == 511) break;  // last step: prediction only

        // gates = [pred | h] @ Wdec^T
        f32x4 acc[4];
        #pragma unroll
        for (int n = 0; n < 4; n++) acc[n] = (f32x4){0.f, 0.f, 0.f, 0.f};
        #pragma unroll
        for (int ks = 0; ks < 8; ks++) {
            #pragma unroll
            for (int n = 0; n < 4; n++) {
                bf16x8 b = *(const bf16x8*)&Bg[(((ks + 4) * 4 + n) * 64 + lane) * 8];
                acc[n] = MFMA16(ha[ks], b, acc[n]);
            }
        }
        const bf16* pst_r = Pst + w * 2176 + l15 * 136 + k0;
        #pragma unroll
        for (int ks = 0; ks < 4; ks++) {
            bf16x8 a = *(const bf16x8*)(pst_r + ks * 32);
            #pragma unroll
            for (int n = 0; n < 4; n++) {
                bf16x8 b = *(const bf16x8*)&Bg[((ks * 4 + n) * 64 + lane) * 8];
                acc[n] = MFMA16(a, b, acc[n]);
            }
        }
        // epilogue
        u32* hw32 = hbuf32 + ((k + 1) & 1) * 32768;
        #pragma unroll
        for (int r = 0; r < 4; r++) {
            float gi = sigm(acc[0][r] + bias_d[0]);
            float gf = sigm(acc[1][r] + bias_d[1]);
            float gg = tanhfast(acc[2][r] + bias_d[2]);
            float go = sigm(acc[3][r] + bias_d[3]);
            c[r] = gf * c[r] + gi * gg;
            float h = go * tanhfast(c[r]);
            unsigned hvv = (unsigned)__builtin_bit_cast(unsigned short, (bf16)h);
            unsigned hp = __shfl_xor(hvv, 1);
            if (!(lane & 1))
                store_h(&hw32[rt * 2048 + htile_w + (hgrp + l4 * 4 + r) * 4 + widx],
                        hvv | (hp << 16));
        }
        // barrier: syncthreads (drains stores) -> flag -> pipelined poll
        stepno++;
        __syncthreads();
        if (tid == 0) store_h(myflag, stepno);
        PIPE_POLL(stepno);
    }
    DRAIN0();
    F_LIVENESS();
}

extern "C" void kernel_launch(void* const* d_in, const int* in_sizes, int n_in,
                              void* d_out, int out_size, void* d_ws, size_t ws_size,
                              hipStream_t stream) {
    const float* x    = (const float*)d_in[0];
    const float* eWih = (const float*)d_in[1];
    const float* eWhh = (const float*)d_in[2];
    const float* ebih = (const float*)d_in[3];
    const float* ebhh = (const float*)d_in[4];
    const float* dWih = (const float*)d_in[5];
    const float* dWhh = (const float*)d_in[6];
    const float* dbih = (const float*)d_in[7];
    const float* dbhh = (const float*)d_in[8];
    const float* linW = (const float*)d_in[9];
    const float* linb = (const float*)d_in[10];
    float* out = (float*)d_out;

    // workspace layout (~1.9 MB)
    bf16* encB = (bf16*)d_ws;            // 393216 bf16
    bf16* decB = encB + 393216;          // 393216 bf16
    bf16* linB = decB + 393216;          // 32768 bf16
    u32*  hbuf = (u32*)(linB + 32768);   // 2 x 16 tiles x 8 ks x 256 u32 (fragment layout)
    u32*  flags = hbuf + 65536;          // 4 rg x 64 words

    hipLaunchKernelGGL(pack_kernel, dim3(3200), dim3(256), 0, stream,
                       eWih, eWhh, dWih, dWhh, linW, encB, decB, linB);
    hipLaunchKernelGGL(zero_kernel, dim3(257), dim3(256), 0, stream, hbuf);
    hipLaunchKernelGGL(lstm_main, dim3(64), dim3(256), 0, stream,
                       x, ebih, ebhh, dbih, dbhh, linb, encB, decB, linB, hbuf, flags, out);
}